// Round 3
// baseline (214.002 us; speedup 1.0000x reference)
//
#include <hip/hip_runtime.h>
#include <hip/hip_fp16.h>

// out[n,a,b] = sigmoid(w2 . leaky(w1 . leaky(u'[n,a,:] - v[n,b,:]) + b1) + b2)
// u' = za.w0^T + b0, v = zb.w0^T (precomputed f16).
// Main GEMM: A = w1 (stationary in VGPRs, rows = hidden1 g), B = hidden0
// fragments built on the fly in packed f16 (no LDS in the GEMM at all).
// Block = 4 waves; wave ws owns g-slice [ws*64, ws*64+64) (2 MFMA row-tiles).
// Grid 512 = n(8) x bblk(8) x aoct(8); each block loops 32 a-values.

typedef float f32x16 __attribute__((ext_vector_type(16)));
typedef _Float16 f16x8 __attribute__((ext_vector_type(8)));

// ---------------------------------------------------------------------------
// Pack u' (f16, linear) and v (f16, MFMA-B-fragment-linear).
// grid 2048 (= n*256 + r), block 256 (thread = hidden channel h)
// ---------------------------------------------------------------------------
__global__ __launch_bounds__(256) void pack_uv_kernel(
    const float* __restrict__ za, const float* __restrict__ zb,
    const float* __restrict__ w0, const float* __restrict__ b0,
    _Float16* __restrict__ upack, _Float16* __restrict__ vpack) {
  int nr = blockIdx.x;              // n*256 + r
  int n = nr >> 8, r = nr & 255;
  __shared__ float arow[64], brow[64];
  int tid = threadIdx.x;
  if (tid < 64) arow[tid] = za[nr * 64 + tid];
  else if (tid < 128) brow[tid - 64] = zb[nr * 64 + (tid - 64)];
  __syncthreads();
  int h = tid;
  const float* w0r = w0 + h * 64;
  float ua = 0.f, vb = 0.f;
#pragma unroll
  for (int c = 0; c < 64; c += 4) {
    float4 w = *reinterpret_cast<const float4*>(w0r + c);
    ua += w.x * arow[c] + w.y * arow[c + 1] + w.z * arow[c + 2] + w.w * arow[c + 3];
    vb += w.x * brow[c] + w.y * brow[c + 1] + w.z * brow[c + 2] + w.w * brow[c + 3];
  }
  upack[nr * 256 + h] = (_Float16)(ua + b0[h]);
  // v B-frag-linear: frag (n, bblk=r>>5, kiter=h>>4); lane = (h&15>>3)*32+(r&31)
  int bblk = r >> 5, lcol = r & 31;
  int kiter = h >> 4, rem = h & 15, lh = rem >> 3, j = rem & 7;
  int lane = lh * 32 + lcol;
  vpack[(((n * 8 + bblk) * 16 + kiter) * 64 + lane) * 8 + j] = (_Float16)vb;
}

// ---------------------------------------------------------------------------
// Pack w1 (256x256 row-major g,k) into A-fragment-linear f16.
// frag (kiter=k>>4, gt=g>>5): lane = ((k&15)>>3)*32 + (g&31), j = k&7
// ---------------------------------------------------------------------------
__global__ __launch_bounds__(256) void pack_w1_kernel(
    const float* __restrict__ w1, _Float16* __restrict__ w1pk) {
  int id = blockIdx.x * 256 + threadIdx.x;   // 0..65535
  int g = id >> 8, k = id & 255;
  int gt = g >> 5, lcol = g & 31;
  int kiter = k >> 4, rem = k & 15, lh = rem >> 3, j = rem & 7;
  int lane = lh * 32 + lcol;
  w1pk[((kiter * 8 + gt) * 64 + lane) * 8 + j] = (_Float16)w1[id];
}

// ---------------------------------------------------------------------------
// Main fused kernel. No LDS for the GEMM; 1KB ping-pong LDS for the w2-dot
// cross-wave reduction only.
// ---------------------------------------------------------------------------
__global__ __launch_bounds__(256, 2) void fused_main(
    const _Float16* __restrict__ upack, const _Float16* __restrict__ vpack,
    const _Float16* __restrict__ w1pk,
    const float* __restrict__ b1, const float* __restrict__ w2,
    const float* __restrict__ b2, float* __restrict__ out) {
  __shared__ float lds_p[2][4][32];
  int bid = blockIdx.x;             // n(3b) | bblk(3b) | aoct(3b)
  int n = bid >> 6;
  int bblk = (bid >> 3) & 7;
  int aoct = bid & 7;
  int tid = threadIdx.x;
  int ws = tid >> 6;                // wave id: g-slice [ws*64, +64)
  int l = tid & 63;
  int l31 = l & 31, lh = l >> 5;

  // Stationary w1 A-fragments: 16 kiters x 2 g-tiles = 128 VGPRs.
  f16x8 w1f[16][2];
#pragma unroll
  for (int kt = 0; kt < 16; ++kt) {
#pragma unroll
    for (int t = 0; t < 2; ++t) {
      int gt = 2 * ws + t;
      w1f[kt][t] = *reinterpret_cast<const f16x8*>(w1pk + ((kt * 8 + gt) * 64 + l) * 8);
    }
  }
  // Bias folded into accumulator init: b1acc[t][r] = b1[g(t,r)]
  f32x16 b1acc[2];
#pragma unroll
  for (int t = 0; t < 2; ++t) {
#pragma unroll
    for (int rg = 0; rg < 4; ++rg) {
      float4 bb = *reinterpret_cast<const float4*>(b1 + (2 * ws + t) * 32 + 8 * rg + 4 * lh);
      b1acc[t][rg * 4 + 0] = bb.x;
      b1acc[t][rg * 4 + 1] = bb.y;
      b1acc[t][rg * 4 + 2] = bb.z;
      b1acc[t][rg * 4 + 3] = bb.w;
    }
  }
  float b2v = b2[0];

  const _Float16 c001 = (_Float16)0.01f;
  const f16x8 c001v = {c001, c001, c001, c001, c001, c001, c001, c001};

  const _Float16* vb = vpack + (size_t)((n * 8 + bblk) * 16) * 512 + l * 8;

  for (int it = 0; it < 32; ++it) {
    int a = aoct * 32 + it;
    const _Float16* ur = upack + (size_t)(n * 256 + a) * 256 + lh * 8;

    f32x16 acc[2];
    acc[0] = b1acc[0];
    acc[1] = b1acc[1];

#pragma unroll
    for (int kt = 0; kt < 16; ++kt) {
      f16x8 uu = *reinterpret_cast<const f16x8*>(ur + kt * 16);
      f16x8 vv = *reinterpret_cast<const f16x8*>(vb + kt * 512);
      f16x8 d = uu - vv;                                   // v_pk_add_f16
      f16x8 r = __builtin_elementwise_max(d, d * c001v);   // leaky (pk mul+max)
      acc[0] = __builtin_amdgcn_mfma_f32_32x32x16_f16(w1f[kt][0], r, acc[0], 0, 0, 0);
      acc[1] = __builtin_amdgcn_mfma_f32_32x32x16_f16(w1f[kt][1], r, acc[1], 0, 0, 0);
    }

    // Epilogue: hidden1 = leaky(acc) (bias already in); p = hidden1 . w2-slice
    float p = 0.f;
#pragma unroll
    for (int t = 0; t < 2; ++t) {
#pragma unroll
      for (int rg = 0; rg < 4; ++rg) {
        float4 ww = *reinterpret_cast<const float4*>(w2 + (2 * ws + t) * 32 + 8 * rg + 4 * lh);
        float h0 = acc[t][rg * 4 + 0]; h0 = fmaxf(h0, 0.01f * h0); p = fmaf(h0, ww.x, p);
        float h1 = acc[t][rg * 4 + 1]; h1 = fmaxf(h1, 0.01f * h1); p = fmaf(h1, ww.y, p);
        float h2 = acc[t][rg * 4 + 2]; h2 = fmaxf(h2, 0.01f * h2); p = fmaf(h2, ww.z, p);
        float h3 = acc[t][rg * 4 + 3]; h3 = fmaxf(h3, 0.01f * h3); p = fmaf(h3, ww.w, p);
      }
    }
    p += __shfl_xor(p, 32, 64);     // fold the two lh halves

    int ph = it & 1;
    if (l < 32) lds_p[ph][ws][l] = p;
    __syncthreads();
    if (ws == 0 && l < 32) {
      float s = lds_p[ph][0][l] + lds_p[ph][1][l] + lds_p[ph][2][l] + lds_p[ph][3][l] + b2v;
      out[(size_t)(n * 256 + a) * 256 + bblk * 32 + l] = 1.f / (1.f + __expf(-s));
    }
    // ping-pong buffer: next iter writes the other phase, no second barrier
  }
}

extern "C" void kernel_launch(void* const* d_in, const int* in_sizes, int n_in,
                              void* d_out, int out_size, void* d_ws, size_t ws_size,
                              hipStream_t stream) {
  const float* za = (const float*)d_in[0];
  const float* zb = (const float*)d_in[1];
  const float* w0 = (const float*)d_in[2];
  const float* b0 = (const float*)d_in[3];
  const float* w1 = (const float*)d_in[4];
  const float* b1 = (const float*)d_in[5];
  const float* w2 = (const float*)d_in[6];
  const float* b2 = (const float*)d_in[7];
  float* out = (float*)d_out;

  char* ws = (char*)d_ws;
  _Float16* upack = (_Float16*)ws;                    // 1 MB
  _Float16* vpack = (_Float16*)(ws + (1u << 20));     // 1 MB
  _Float16* w1pk  = (_Float16*)(ws + (2u << 20));     // 128 KB

  pack_uv_kernel<<<2048, 256, 0, stream>>>(za, zb, w0, b0, upack, vpack);
  pack_w1_kernel<<<256, 256, 0, stream>>>(w1, w1pk);
  fused_main<<<512, 256, 0, stream>>>(upack, vpack, w1pk, b1, w2, b2, out);
}